// Round 1
// baseline (361.804 us; speedup 1.0000x reference)
//
#include <hip/hip_runtime.h>

typedef unsigned short u16;
typedef __bf16 bf16x8 __attribute__((ext_vector_type(8)));
typedef float f32x4 __attribute__((ext_vector_type(4)));
typedef unsigned short u16x4 __attribute__((ext_vector_type(4)));
typedef unsigned short u16x8 __attribute__((ext_vector_type(8)));

#define DIM 1024
#define HEADS 16
#define HD 64
#define SEQ 2048
#define BATCH 4
#define NROWS (BATCH*SEQ)
#define ATT_SCALE 0.125f

__device__ __forceinline__ u16 f2bf(float f) {
  union { float f; unsigned u; } v; v.f = f;
  unsigned r = v.u + 0x7FFFu + ((v.u >> 16) & 1u);   // RNE
  return (u16)(r >> 16);
}

__device__ __forceinline__ f32x4 mfma16(bf16x8 a, bf16x8 b, f32x4 c) {
  return __builtin_amdgcn_mfma_f32_16x16x32_bf16(a, b, c, 0, 0, 0);
}

// ---------------- cast x (f32 -> bf16), 4 elems/thread ----------------
__global__ __launch_bounds__(256) void cast_f32_bf16(const float* __restrict__ in,
                                                     u16* __restrict__ out) {
  int i = blockIdx.x * 256 + threadIdx.x;
  float4 v = ((const float4*)in)[i];
  u16x4 o = { f2bf(v.x), f2bf(v.y), f2bf(v.z), f2bf(v.w) };
  *(u16x4*)(out + (size_t)i * 4) = o;
}

// ------------- transpose+cast: in[R][C] f32 -> out[C][R] bf16 -------------
__global__ __launch_bounds__(256) void transpose_cast(const float* __restrict__ in,
                                                      u16* __restrict__ out,
                                                      int R, int C) {
  __shared__ u16 tile[64][65];
  int c0 = blockIdx.x * 64, r0 = blockIdx.y * 64;
  int tid = threadIdx.x;
#pragma unroll
  for (int i = 0; i < 16; ++i) {
    int idx = tid + i * 256;
    int r = idx >> 6, c = idx & 63;
    tile[c][r] = f2bf(in[(size_t)(r0 + r) * C + c0 + c]);
  }
  __syncthreads();
#pragma unroll
  for (int i = 0; i < 16; ++i) {
    int idx = tid + i * 256;
    int r = idx >> 6, c = idx & 63;
    out[(size_t)(c0 + r) * R + r0 + c] = tile[r][c];
  }
}

// ---------------- GEMM: C[M,N] = A[M,K] (bf16) @ BT[N,K]^T (bf16) ----------------
// 128x128 tile, BK=64, 4 waves, each wave a 64x64 quadrant (4x4 of 16x16x32 MFMA).
template<int OUT_F32>
__global__ __launch_bounds__(256) void gemm_bt(const u16* __restrict__ A,
                                               const u16* __restrict__ BT,
                                               void* __restrict__ Cout,
                                               const float* __restrict__ bias,
                                               int M, int N, int K) {
  __shared__ __align__(16) u16 As[128 * 64];
  __shared__ __align__(16) u16 Bs[128 * 64];
  const int tid = threadIdx.x;
  const int l = tid & 63, w = tid >> 6, g = l >> 4, ln = l & 15;
  const int m0 = blockIdx.y * 128, n0 = blockIdx.x * 128;
  const int wr = w >> 1, wc = w & 1;
  f32x4 acc[4][4];
#pragma unroll
  for (int i = 0; i < 4; ++i)
#pragma unroll
    for (int j = 0; j < 4; ++j) acc[i][j] = (f32x4){0.f, 0.f, 0.f, 0.f};

  const char* Ab = (const char*)A;
  const char* Bb = (const char*)BT;
  const size_t strideAB = (size_t)K * 2;   // bytes per row
  const int nk = K >> 6;
  for (int kt = 0; kt < nk; ++kt) {
    const size_t kofs = (size_t)kt * 128;  // byte offset along K
    // reg-stage 128x64 bf16 tiles of A and B
#pragma unroll
    for (int is = 0; is < 4; ++is) {
      int ofs = is * 4096 + tid * 16;      // byte offset in tile
      int r = ofs >> 7, cb = ofs & 127;
      bf16x8 va = *(const bf16x8*)(Ab + (size_t)(m0 + r) * strideAB + kofs + cb);
      bf16x8 vb = *(const bf16x8*)(Bb + (size_t)(n0 + r) * strideAB + kofs + cb);
      *(bf16x8*)((char*)As + ofs) = va;
      *(bf16x8*)((char*)Bs + ofs) = vb;
    }
    __syncthreads();
#pragma unroll
    for (int kk = 0; kk < 2; ++kk) {
      bf16x8 af[4], bfr[4];
#pragma unroll
      for (int i = 0; i < 4; ++i) {
        af[i]  = *(const bf16x8*)(As + (wr * 64 + i * 16 + ln) * 64 + kk * 32 + g * 8);
        bfr[i] = *(const bf16x8*)(Bs + (wc * 64 + i * 16 + ln) * 64 + kk * 32 + g * 8);
      }
#pragma unroll
      for (int mi = 0; mi < 4; ++mi)
#pragma unroll
        for (int ni = 0; ni < 4; ++ni)
          acc[mi][ni] = mfma16(af[mi], bfr[ni], acc[mi][ni]);
    }
    __syncthreads();
  }
  // epilogue: C row = m0+wr*64+mi*16+4g+j, col = n0+wc*64+ni*16+ln
#pragma unroll
  for (int mi = 0; mi < 4; ++mi) {
#pragma unroll
    for (int ni = 0; ni < 4; ++ni) {
      int col = n0 + wc * 64 + ni * 16 + ln;
#pragma unroll
      for (int j = 0; j < 4; ++j) {
        int row = m0 + wr * 64 + mi * 16 + g * 4 + j;
        float v = acc[mi][ni][j];
        if (OUT_F32) {
          ((float*)Cout)[(size_t)row * N + col] = v + bias[col];
        } else {
          ((u16*)Cout)[(size_t)row * N + col] = f2bf(v);
        }
      }
    }
  }
}

// ---------------- flash attention ----------------
// grid (qt=32, h=16, b=4), 256 threads = 4 waves; wave owns 16 q-rows.
// Swapped QK^T: S^T = mfma(K, Q) so lane `ln` owns q-row ln's logits (16/lane/tile).
// O^T accumulated in registers (col = q = ln). P routed via per-wave LDS to B-frag layout.
__global__ __launch_bounds__(256) void attn_kernel(const u16* __restrict__ qkv,
                                                   u16* __restrict__ obuf) {
  __shared__ __align__(16) u16 k_lds[64 * 72];        // [kv][d], stride 72 (144B, 16B-aligned rows)
  __shared__ __align__(16) u16 v_lds[64 * 72];        // [d][kv] (transposed)
  __shared__ __align__(16) u16 p_lds[4 * 16 * 72];    // per-wave [q=16][kv=64] P^T
  const int qt = blockIdx.x, h = blockIdx.y, b = blockIdx.z;
  const int tid = threadIdx.x;
  const int w = tid >> 6, l = tid & 63, g = l >> 4, ln = l & 15;
  const int qrow = qt * 64 + w * 16 + ln;
  const size_t rs = 3 * DIM;
  const u16* qb = qkv + (size_t)(b * SEQ + qrow) * rs + h * HD;
  bf16x8 qf0 = *(const bf16x8*)(qb + g * 8);
  bf16x8 qf1 = *(const bf16x8*)(qb + 32 + g * 8);

  float m = -1e30f, lsum = 0.f;
  f32x4 of[4];
#pragma unroll
  for (int i = 0; i < 4; ++i) of[i] = (f32x4){0.f, 0.f, 0.f, 0.f};
  u16* pw = p_lds + w * (16 * 72);

  for (int kv0 = 0; kv0 < SEQ; kv0 += 64) {
    // stage K [64][64] linear-ish (padded) and V^T [d][kv]
#pragma unroll
    for (int ic = 0; ic < 2; ++ic) {
      int cidx = tid + ic * 256;
      int r = cidx >> 3, c8 = cidx & 7;
      const u16* kp = qkv + (size_t)(b * SEQ + kv0 + r) * rs + DIM + h * HD + c8 * 8;
      *(u16x8*)(k_lds + r * 72 + c8 * 8) = *(const u16x8*)kp;
      u16x8 vv = *(const u16x8*)(kp + DIM);
#pragma unroll
      for (int e = 0; e < 8; ++e) v_lds[(c8 * 8 + e) * 72 + r] = vv[e];
    }
    __syncthreads();

    // S^T = K @ Q^T : per wave 4 kv-frags x 2 k-slices
    f32x4 sacc[4];
#pragma unroll
    for (int f = 0; f < 4; ++f) sacc[f] = (f32x4){0.f, 0.f, 0.f, 0.f};
#pragma unroll
    for (int f = 0; f < 4; ++f) {
      bf16x8 a0 = *(const bf16x8*)(k_lds + (f * 16 + ln) * 72 + g * 8);
      bf16x8 a1 = *(const bf16x8*)(k_lds + (f * 16 + ln) * 72 + 32 + g * 8);
      sacc[f] = mfma16(a0, qf0, sacc[f]);
      sacc[f] = mfma16(a1, qf1, sacc[f]);
    }

    // online softmax: lane ln owns q-row ln; its 16 logits are kv = 16f + 4g + j
    float sv[16];
    float tm = -1e30f;
#pragma unroll
    for (int f = 0; f < 4; ++f)
#pragma unroll
      for (int j = 0; j < 4; ++j) {
        float s = sacc[f][j] * ATT_SCALE;
        sv[f * 4 + j] = s;
        tm = fmaxf(tm, s);
      }
    tm = fmaxf(tm, __shfl_xor(tm, 16));
    tm = fmaxf(tm, __shfl_xor(tm, 32));
    float mn = fmaxf(m, tm);
    float resc = __expf(m - mn);
    float ps = 0.f;
    u16 pb[16];
#pragma unroll
    for (int i = 0; i < 16; ++i) {
      float p = __expf(sv[i] - mn);
      ps += p;
      pb[i] = f2bf(p);
    }
    ps += __shfl_xor(ps, 16);
    ps += __shfl_xor(ps, 32);
    lsum = lsum * resc + ps;
    m = mn;
#pragma unroll
    for (int fd = 0; fd < 4; ++fd) of[fd] *= resc;

    // write P^T to per-wave LDS: [q=ln][kv = 16f+4g+j]
#pragma unroll
    for (int f = 0; f < 4; ++f) {
      u16x4 pk = { pb[f * 4], pb[f * 4 + 1], pb[f * 4 + 2], pb[f * 4 + 3] };
      *(u16x4*)(pw + ln * 72 + f * 16 + g * 4) = pk;
    }
    // PV: O^T += V^T @ P^T
    bf16x8 bp0 = *(const bf16x8*)(pw + ln * 72 + g * 8);
    bf16x8 bp1 = *(const bf16x8*)(pw + ln * 72 + 32 + g * 8);
#pragma unroll
    for (int fd = 0; fd < 4; ++fd) {
      bf16x8 a0 = *(const bf16x8*)(v_lds + (fd * 16 + ln) * 72 + g * 8);
      bf16x8 a1 = *(const bf16x8*)(v_lds + (fd * 16 + ln) * 72 + 32 + g * 8);
      of[fd] = mfma16(a0, bp0, of[fd]);
      of[fd] = mfma16(a1, bp1, of[fd]);
    }
    __syncthreads();
  }

  // epilogue: o[q][d] = O^T[d][q] / l ; d = fd*16 + 4g + j
  float linv = 1.f / lsum;
  u16* orow = obuf + (size_t)(b * SEQ + qrow) * DIM + h * HD;
#pragma unroll
  for (int fd = 0; fd < 4; ++fd) {
    u16x4 ov = { f2bf(of[fd][0] * linv), f2bf(of[fd][1] * linv),
                 f2bf(of[fd][2] * linv), f2bf(of[fd][3] * linv) };
    *(u16x4*)(orow + fd * 16 + g * 4) = ov;
  }
}

extern "C" void kernel_launch(void* const* d_in, const int* in_sizes, int n_in,
                              void* d_out, int out_size, void* d_ws, size_t ws_size,
                              hipStream_t stream) {
  const float* x     = (const float*)d_in[0];
  const float* w_in  = (const float*)d_in[1];
  const float* w_out = (const float*)d_in[2];
  const float* b_out = (const float*)d_in[3];
  float* out = (float*)d_out;

  char* ws = (char*)d_ws;
  u16* xb     = (u16*)(ws);                               // 16 MiB: x as bf16 [8192][1024]
  u16* w_inT  = (u16*)(ws + (size_t)16 * 1024 * 1024);    //  6 MiB: [3072][1024]
  u16* w_outT = (u16*)(ws + (size_t)22 * 1024 * 1024);    //  2 MiB: [1024][1024]
  u16* qkv    = (u16*)(ws + (size_t)24 * 1024 * 1024);    // 48 MiB: [8192][3072]
  u16* obuf   = (u16*)(ws + (size_t)72 * 1024 * 1024);    // 16 MiB: [8192][1024]

  cast_f32_bf16<<<8192, 256, 0, stream>>>(x, xb);
  transpose_cast<<<dim3(48, 16), 256, 0, stream>>>(w_in, w_inT, 1024, 3072);
  transpose_cast<<<dim3(16, 16), 256, 0, stream>>>(w_out, w_outT, 1024, 1024);
  // qkv = x @ w_in  (bf16 out)
  gemm_bt<0><<<dim3(24, 64), 256, 0, stream>>>(xb, w_inT, qkv, nullptr, NROWS, 3 * DIM, DIM);
  // attention -> obuf [8192][1024] bf16 (heads merged)
  attn_kernel<<<dim3(32, HEADS, BATCH), 256, 0, stream>>>(qkv, obuf);
  // out = obuf @ w_out + b_out (fp32 out)
  gemm_bt<1><<<dim3(8, 64), 256, 0, stream>>>(obuf, w_outT, out, b_out, NROWS, DIM, DIM);
}

// Round 3
// 277.265 us; speedup vs baseline: 1.3049x; 1.3049x over previous
//
#include <hip/hip_runtime.h>

typedef unsigned short u16;
typedef __bf16 bf16x8 __attribute__((ext_vector_type(8)));
typedef float f32x4 __attribute__((ext_vector_type(4)));
typedef unsigned short u16x4 __attribute__((ext_vector_type(4)));
typedef unsigned short u16x8 __attribute__((ext_vector_type(8)));

#define DIM 1024
#define HEADS 16
#define HD 64
#define SEQ 2048
#define BATCH 4
#define NROWS (BATCH*SEQ)
#define ATT_SCALE 0.125f

__device__ __forceinline__ u16 f2bf(float f) {
  union { float f; unsigned u; } v; v.f = f;
  unsigned r = v.u + 0x7FFFu + ((v.u >> 16) & 1u);   // RNE
  return (u16)(r >> 16);
}

__device__ __forceinline__ f32x4 mfma16(bf16x8 a, bf16x8 b, f32x4 c) {
  return __builtin_amdgcn_mfma_f32_16x16x32_bf16(a, b, c, 0, 0, 0);
}

// async global->LDS, 16B per lane; dst must be wave-uniform (HW adds lane*16)
__device__ __forceinline__ void gl_lds16(const void* g, void* l) {
  __builtin_amdgcn_global_load_lds(
      (const __attribute__((address_space(1))) void*)g,
      (__attribute__((address_space(3))) void*)l, 16, 0, 0);
}

// ---------------- cast x (f32 -> bf16), 4 elems/thread ----------------
__global__ __launch_bounds__(256) void cast_f32_bf16(const float* __restrict__ in,
                                                     u16* __restrict__ out) {
  int i = blockIdx.x * 256 + threadIdx.x;
  float4 v = ((const float4*)in)[i];
  u16x4 o = { f2bf(v.x), f2bf(v.y), f2bf(v.z), f2bf(v.w) };
  *(u16x4*)(out + (size_t)i * 4) = o;
}

// ------------- transpose+cast: in[R][C] f32 -> out[C][R] bf16 -------------
__global__ __launch_bounds__(256) void transpose_cast(const float* __restrict__ in,
                                                      u16* __restrict__ out,
                                                      int R, int C) {
  __shared__ u16 tile[64][65];
  int c0 = blockIdx.x * 64, r0 = blockIdx.y * 64;
  int tid = threadIdx.x;
#pragma unroll
  for (int i = 0; i < 16; ++i) {
    int idx = tid + i * 256;
    int r = idx >> 6, c = idx & 63;
    tile[c][r] = f2bf(in[(size_t)(r0 + r) * C + c0 + c]);
  }
  __syncthreads();
#pragma unroll
  for (int i = 0; i < 16; ++i) {
    int idx = tid + i * 256;
    int r = idx >> 6, c = idx & 63;
    out[(size_t)(c0 + r) * R + r0 + c] = tile[r][c];
  }
}

// ------------- V pre-transpose: vT[(bh*64+d)*2048 + kv] = qkv[b,kv][2048+h*64+d] -------------
// u32 2x2 trick: pack kv-pairs so LDS traffic is u32 and global writes are u32-coalesced.
__global__ __launch_bounds__(256) void transpose_v(const u16* __restrict__ qkv,
                                                   u16* __restrict__ vT) {
  __shared__ unsigned t32[64][37];   // [d][kv2], pad 37 (gcd(5,32)=1 -> conflict-free)
  const int t = blockIdx.x, bh = blockIdx.y;
  const int b = bh >> 4, h = bh & 15;
  const u16* src = qkv + ((size_t)(b * SEQ + t * 64)) * 3072 + 2048 + h * 64;
  const int tid = threadIdx.x;
#pragma unroll
  for (int i = 0; i < 8; ++i) {      // 32 kv-pairs x 64 d
    int lin = tid + i * 256;
    int r2 = lin >> 6, c = lin & 63;
    unsigned lo = src[(size_t)(2 * r2) * 3072 + c];
    unsigned hi = src[(size_t)(2 * r2 + 1) * 3072 + c];
    t32[c][r2] = lo | (hi << 16);
  }
  __syncthreads();
  unsigned* dst = (unsigned*)(vT + (size_t)bh * 64 * 2048);
#pragma unroll
  for (int i = 0; i < 8; ++i) {      // 64 d x 32 kv2
    int lin = tid + i * 256;
    int d = lin >> 5, r2 = lin & 31;
    dst[(size_t)d * 1024 + t * 32 + r2] = t32[d][r2];
  }
}

// ---------------- GEMM: C[M,N] = A[M,K] (bf16) @ BT[N,K]^T (bf16) ----------------
// 128x128 tile, BK=64, 4 waves; staging via global_load_lds width=16 (m97 recipe).
template<int OUT_F32>
__global__ __launch_bounds__(256) void gemm_bt(const u16* __restrict__ A,
                                               const u16* __restrict__ BT,
                                               void* __restrict__ Cout,
                                               const float* __restrict__ bias,
                                               int M, int N, int K) {
  __shared__ __align__(16) u16 As[128 * 64];
  __shared__ __align__(16) u16 Bs[128 * 64];
  const int tid = threadIdx.x;
  const int l = tid & 63, w = tid >> 6, g = l >> 4, ln = l & 15;
  const int m0 = blockIdx.y * 128, n0 = blockIdx.x * 128;
  const int wr = w >> 1, wc = w & 1;
  f32x4 acc[4][4];
#pragma unroll
  for (int i = 0; i < 4; ++i)
#pragma unroll
    for (int j = 0; j < 4; ++j) acc[i][j] = (f32x4){0.f, 0.f, 0.f, 0.f};

  // staging geometry: dest byte ofs o = is*4096 + tid*16 -> row = is*32 + tid/8, col8 = tid%8
  const int srow = tid >> 3;
  const int scol = (tid & 7) * 8;                 // elements
  const u16* Asrc = A  + (size_t)(m0 + srow) * K + scol;
  const u16* Bsrc = BT + (size_t)(n0 + srow) * K + scol;
  char* AsB = (char*)As + (size_t)w * 1024;
  char* BsB = (char*)Bs + (size_t)w * 1024;

  const int nk = K >> 6;
  for (int kt = 0; kt < nk; ++kt) {
    const u16* a0 = Asrc + kt * 64;
    const u16* b0 = Bsrc + kt * 64;
#pragma unroll
    for (int is = 0; is < 4; ++is) {
      gl_lds16(a0 + (size_t)is * 32 * K, AsB + is * 4096);
      gl_lds16(b0 + (size_t)is * 32 * K, BsB + is * 4096);
    }
    __syncthreads();
#pragma unroll
    for (int kk = 0; kk < 2; ++kk) {
      bf16x8 af[4], bfr[4];
#pragma unroll
      for (int i = 0; i < 4; ++i) {
        af[i]  = *(const bf16x8*)(As + (wr * 64 + i * 16 + ln) * 64 + kk * 32 + g * 8);
        bfr[i] = *(const bf16x8*)(Bs + (wc * 64 + i * 16 + ln) * 64 + kk * 32 + g * 8);
      }
#pragma unroll
      for (int mi = 0; mi < 4; ++mi)
#pragma unroll
        for (int ni = 0; ni < 4; ++ni)
          acc[mi][ni] = mfma16(af[mi], bfr[ni], acc[mi][ni]);
    }
    __syncthreads();
  }
  // epilogue: C row = m0+wr*64+mi*16+4g+j, col = n0+wc*64+ni*16+ln
#pragma unroll
  for (int mi = 0; mi < 4; ++mi) {
#pragma unroll
    for (int ni = 0; ni < 4; ++ni) {
      int col = n0 + wc * 64 + ni * 16 + ln;
#pragma unroll
      for (int j = 0; j < 4; ++j) {
        int row = m0 + wr * 64 + mi * 16 + g * 4 + j;
        float v = acc[mi][ni][j];
        if (OUT_F32) {
          ((float*)Cout)[(size_t)row * N + col] = v + bias[col];
        } else {
          ((u16*)Cout)[(size_t)row * N + col] = f2bf(v);
        }
      }
    }
  }
}

// ---------------- flash attention ----------------
// grid (qt=32, h=16, b=4), 256 threads = 4 waves; wave owns 16 q-rows.
// Swapped QK^T (S^T = mfma(K,Q)): lane ln owns q-row ln; P stays in registers.
// PV uses consistent k-permutation pi(g,s) = 16*(s>>2) + 4g + (s&3) on BOTH operands:
//   A = V^T rows from XOR-swizzled v_lds (staged from pre-transposed vT), 2x ds_read_b64;
//   B = lane-local P values pf[kk].u[s] (no LDS routing).
// K and V^T both staged linear [64 rows][128B] with byte ^= (row&7)<<4 swizzle,
// via global_load_lds with inverse-swizzled SOURCE address (rule #21).
__global__ __launch_bounds__(256) void attn_kernel(const u16* __restrict__ qkv,
                                                   const u16* __restrict__ vT,
                                                   u16* __restrict__ obuf) {
  __shared__ __align__(16) u16 k_lds[64 * 64];
  __shared__ __align__(16) u16 v_lds[64 * 64];
  const int qt = blockIdx.x, h = blockIdx.y, b = blockIdx.z;
  const int tid = threadIdx.x;
  const int w = tid >> 6, l = tid & 63, g = l >> 4, ln = l & 15;
  const int qrow = qt * 64 + w * 16 + ln;
  const size_t rs = 3 * DIM;
  const u16* qb = qkv + (size_t)(b * SEQ + qrow) * rs + h * HD;
  bf16x8 qf0 = *(const bf16x8*)(qb + g * 8);
  bf16x8 qf1 = *(const bf16x8*)(qb + 32 + g * 8);

  // staging geometry: dest o = it*4096 + tid*16 -> row = it*32 + tid/8, destcol=(tid&7)*16B
  // source col = destcol ^ ((row&7)<<4)   (inverse-swizzle source)
  const int krow = tid >> 3;
  const int ksrccol = ((((tid & 7) << 4) ^ ((krow & 7) << 4))) >> 1;  // elements
  const u16* kbase = qkv + (size_t)b * SEQ * rs + DIM + h * HD;
  const u16* vtb = vT + (size_t)(b * HEADS + h) * 64 * 2048;
  char* kdst = (char*)k_lds + (size_t)w * 1024;
  char* vdst = (char*)v_lds + (size_t)w * 1024;

  const int swz = (ln & 7) << 4;                   // read-side swizzle (row&7 == ln&7)

  float m = -1e30f, lsum = 0.f;
  f32x4 of[4];
#pragma unroll
  for (int i = 0; i < 4; ++i) of[i] = (f32x4){0.f, 0.f, 0.f, 0.f};

  for (int kv0 = 0; kv0 < SEQ; kv0 += 64) {
    // ---- stage K and V^T tiles (both swizzled) via global_load_lds ----
    const u16* ks0 = kbase + (size_t)(kv0 + krow) * rs + ksrccol;
    const u16* vs0 = vtb + (size_t)krow * 2048 + kv0 + ksrccol;
    gl_lds16(ks0, kdst);
    gl_lds16(ks0 + (size_t)32 * rs, kdst + 4096);
    gl_lds16(vs0, vdst);
    gl_lds16(vs0 + (size_t)32 * 2048, vdst + 4096);
    __syncthreads();

    // ---- S^T = K @ Q^T ----
    f32x4 sacc[4];
#pragma unroll
    for (int f = 0; f < 4; ++f) sacc[f] = (f32x4){0.f, 0.f, 0.f, 0.f};
#pragma unroll
    for (int f = 0; f < 4; ++f) {
      const char* kr = (const char*)k_lds + (f * 16 + ln) * 128;
      bf16x8 a0 = *(const bf16x8*)(kr + ((g * 16) ^ swz));
      bf16x8 a1 = *(const bf16x8*)(kr + ((64 | (g * 16)) ^ swz));
      sacc[f] = mfma16(a0, qf0, sacc[f]);
      sacc[f] = mfma16(a1, qf1, sacc[f]);
    }

    // ---- online softmax (lane ln owns q-row ln; kv = f*16 + g*4 + j) ----
    float tm = -1e30f;
#pragma unroll
    for (int f = 0; f < 4; ++f)
#pragma unroll
      for (int j = 0; j < 4; ++j) {
        float s = sacc[f][j] * ATT_SCALE;
        sacc[f][j] = s;
        tm = fmaxf(tm, s);
      }
    tm = fmaxf(tm, __shfl_xor(tm, 16));
    tm = fmaxf(tm, __shfl_xor(tm, 32));
    float mn = fmaxf(m, tm);
    float resc = __expf(m - mn);
    float ps = 0.f;
    union pu { u16x8 u; bf16x8 b; } pf[2];
#pragma unroll
    for (int f = 0; f < 4; ++f)
#pragma unroll
      for (int j = 0; j < 4; ++j) {
        float p = __expf(sacc[f][j] - mn);
        ps += p;
        pf[f >> 1].u[(f & 1) * 4 + j] = f2bf(p);   // slot s=(f&1)*4+j of frag kk=f>>1
      }
    ps += __shfl_xor(ps, 16);
    ps += __shfl_xor(ps, 32);
    lsum = lsum * resc + ps;
    m = mn;
#pragma unroll
    for (int fd = 0; fd < 4; ++fd) of[fd] *= resc;

    // ---- PV: O^T += V^T @ P^T ----
    // A slot s of frag (fd,kk): V[kv0 + 32kk + 16*(s>>2) + 4g + (s&3)][d=fd*16+ln]
    //  = v_lds row (fd*16+ln), bytes (64kk + 16*(s>>2)*2 + 8g) ^ swz  (two b64 reads)
#pragma unroll
    for (int kk = 0; kk < 2; ++kk) {
#pragma unroll
      for (int fd = 0; fd < 4; ++fd) {
        const char* vr = (const char*)v_lds + (fd * 16 + ln) * 128;
        u16x4 lo = *(const u16x4*)(vr + ((64 * kk + 8 * g) ^ swz));
        u16x4 hi = *(const u16x4*)(vr + ((64 * kk + 32 + 8 * g) ^ swz));
        union { u16x8 u; bf16x8 b; } fa;
        fa.u = (u16x8){ lo[0], lo[1], lo[2], lo[3], hi[0], hi[1], hi[2], hi[3] };
        of[fd] = mfma16(fa.b, pf[kk].b, of[fd]);
      }
    }
    __syncthreads();
  }

  // epilogue: o[q][d] = O^T[d][q] / l ; d = fd*16 + 4g + j
  float linv = 1.f / lsum;
  u16* orow = obuf + (size_t)(b * SEQ + qrow) * DIM + h * HD;
#pragma unroll
  for (int fd = 0; fd < 4; ++fd) {
    u16x4 ov = { f2bf(of[fd][0] * linv), f2bf(of[fd][1] * linv),
                 f2bf(of[fd][2] * linv), f2bf(of[fd][3] * linv) };
    *(u16x4*)(orow + fd * 16 + g * 4) = ov;
  }
}

extern "C" void kernel_launch(void* const* d_in, const int* in_sizes, int n_in,
                              void* d_out, int out_size, void* d_ws, size_t ws_size,
                              hipStream_t stream) {
  const float* x     = (const float*)d_in[0];
  const float* w_in  = (const float*)d_in[1];
  const float* w_out = (const float*)d_in[2];
  const float* b_out = (const float*)d_in[3];
  float* out = (float*)d_out;

  char* ws = (char*)d_ws;
  u16* xb     = (u16*)(ws);                               // 16 MiB: x bf16 (dead after gemm1)
  u16* vT     = (u16*)(ws);                               // 16 MiB: aliases xb (written after gemm1)
  u16* w_inT  = (u16*)(ws + (size_t)16 * 1024 * 1024);    //  6 MiB: [3072][1024]
  u16* w_outT = (u16*)(ws + (size_t)22 * 1024 * 1024);    //  2 MiB: [1024][1024]
  u16* qkv    = (u16*)(ws + (size_t)24 * 1024 * 1024);    // 48 MiB: [8192][3072]
  u16* obuf   = (u16*)(ws + (size_t)72 * 1024 * 1024);    // 16 MiB: [8192][1024]

  cast_f32_bf16<<<8192, 256, 0, stream>>>(x, xb);
  transpose_cast<<<dim3(48, 16), 256, 0, stream>>>(w_in, w_inT, 1024, 3072);
  transpose_cast<<<dim3(16, 16), 256, 0, stream>>>(w_out, w_outT, 1024, 1024);
  // qkv = x @ w_in  (bf16 out)
  gemm_bt<0><<<dim3(24, 64), 256, 0, stream>>>(xb, w_inT, qkv, nullptr, NROWS, 3 * DIM, DIM);
  // vT[bh][d][kv] from qkv's V columns (xb is dead now)
  transpose_v<<<dim3(32, 64), 256, 0, stream>>>(qkv, vT);
  // attention -> obuf [8192][1024] bf16 (heads merged)
  attn_kernel<<<dim3(32, HEADS, BATCH), 256, 0, stream>>>(qkv, vT, obuf);
  // out = obuf @ w_out + b_out (fp32 out)
  gemm_bt<1><<<dim3(8, 64), 256, 0, stream>>>(obuf, w_outT, out, b_out, NROWS, DIM, DIM);
}

// Round 4
// 255.278 us; speedup vs baseline: 1.4173x; 1.0861x over previous
//
#include <hip/hip_runtime.h>

typedef unsigned short u16;
typedef __bf16 bf16x8 __attribute__((ext_vector_type(8)));
typedef float f32x4 __attribute__((ext_vector_type(4)));
typedef unsigned short u16x4 __attribute__((ext_vector_type(4)));
typedef unsigned short u16x8 __attribute__((ext_vector_type(8)));

#define DIM 1024
#define HEADS 16
#define HD 64
#define SEQ 2048
#define BATCH 4
#define NROWS (BATCH*SEQ)
// raw-logit exp2 constant: 0.125 * log2(e)
#define C2 0.18033688f
#define DEFER_THR 30.0f

__device__ __forceinline__ u16 f2bf(float f) {
  union { float f; unsigned u; } v; v.f = f;
  unsigned r = v.u + 0x7FFFu + ((v.u >> 16) & 1u);   // RNE
  return (u16)(r >> 16);
}

__device__ __forceinline__ unsigned cvt_pk_bf16(float lo, float hi) {
  unsigned r;
  asm("v_cvt_pk_bf16_f32 %0, %1, %2" : "=v"(r) : "v"(lo), "v"(hi));
  return r;
}

__device__ __forceinline__ f32x4 mfma16(bf16x8 a, bf16x8 b, f32x4 c) {
  return __builtin_amdgcn_mfma_f32_16x16x32_bf16(a, b, c, 0, 0, 0);
}

// async global->LDS, 16B per lane; dst must be wave-uniform (HW adds lane*16)
__device__ __forceinline__ void gl_lds16(const void* g, void* l) {
  __builtin_amdgcn_global_load_lds(
      (const __attribute__((address_space(1))) void*)g,
      (__attribute__((address_space(3))) void*)l, 16, 0, 0);
}

// ---------------- cast x (f32 -> bf16), 4 elems/thread ----------------
__global__ __launch_bounds__(256) void cast_f32_bf16(const float* __restrict__ in,
                                                     u16* __restrict__ out) {
  int i = blockIdx.x * 256 + threadIdx.x;
  float4 v = ((const float4*)in)[i];
  u16x4 o = { f2bf(v.x), f2bf(v.y), f2bf(v.z), f2bf(v.w) };
  *(u16x4*)(out + (size_t)i * 4) = o;
}

// ------------- transpose+cast: in[R][C] f32 -> out[C][R] bf16 -------------
__global__ __launch_bounds__(256) void transpose_cast(const float* __restrict__ in,
                                                      u16* __restrict__ out,
                                                      int R, int C) {
  __shared__ u16 tile[64][65];
  int c0 = blockIdx.x * 64, r0 = blockIdx.y * 64;
  int tid = threadIdx.x;
#pragma unroll
  for (int i = 0; i < 16; ++i) {
    int idx = tid + i * 256;
    int r = idx >> 6, c = idx & 63;
    tile[c][r] = f2bf(in[(size_t)(r0 + r) * C + c0 + c]);
  }
  __syncthreads();
#pragma unroll
  for (int i = 0; i < 16; ++i) {
    int idx = tid + i * 256;
    int r = idx >> 6, c = idx & 63;
    out[(size_t)(c0 + r) * R + r0 + c] = tile[r][c];
  }
}

// ------------- V pre-transpose: vT[(bh*64+d)*2048 + kv] = qkv[b,kv][2048+h*64+d] -------------
__global__ __launch_bounds__(256) void transpose_v(const u16* __restrict__ qkv,
                                                   u16* __restrict__ vT) {
  __shared__ unsigned t32[64][37];
  const int t = blockIdx.x, bh = blockIdx.y;
  const int b = bh >> 4, h = bh & 15;
  const u16* src = qkv + ((size_t)(b * SEQ + t * 64)) * 3072 + 2048 + h * 64;
  const int tid = threadIdx.x;
#pragma unroll
  for (int i = 0; i < 8; ++i) {
    int lin = tid + i * 256;
    int r2 = lin >> 6, c = lin & 63;
    unsigned lo = src[(size_t)(2 * r2) * 3072 + c];
    unsigned hi = src[(size_t)(2 * r2 + 1) * 3072 + c];
    t32[c][r2] = lo | (hi << 16);
  }
  __syncthreads();
  unsigned* dst = (unsigned*)(vT + (size_t)bh * 64 * 2048);
#pragma unroll
  for (int i = 0; i < 8; ++i) {
    int lin = tid + i * 256;
    int d = lin >> 5, r2 = lin & 31;
    dst[(size_t)d * 1024 + t * 32 + r2] = t32[d][r2];
  }
}

// ---------------- GEMM: C[M,N] = A[M,K] (bf16) @ BT[N,K]^T (bf16) ----------------
template<int OUT_F32>
__global__ __launch_bounds__(256) void gemm_bt(const u16* __restrict__ A,
                                               const u16* __restrict__ BT,
                                               void* __restrict__ Cout,
                                               const float* __restrict__ bias,
                                               int M, int N, int K) {
  __shared__ __align__(16) u16 As[128 * 64];
  __shared__ __align__(16) u16 Bs[128 * 64];
  const int tid = threadIdx.x;
  const int l = tid & 63, w = tid >> 6, g = l >> 4, ln = l & 15;
  const int m0 = blockIdx.y * 128, n0 = blockIdx.x * 128;
  const int wr = w >> 1, wc = w & 1;
  f32x4 acc[4][4];
#pragma unroll
  for (int i = 0; i < 4; ++i)
#pragma unroll
    for (int j = 0; j < 4; ++j) acc[i][j] = (f32x4){0.f, 0.f, 0.f, 0.f};

  const int srow = tid >> 3;
  const int scol = (tid & 7) * 8;
  const u16* Asrc = A  + (size_t)(m0 + srow) * K + scol;
  const u16* Bsrc = BT + (size_t)(n0 + srow) * K + scol;
  char* AsB = (char*)As + (size_t)w * 1024;
  char* BsB = (char*)Bs + (size_t)w * 1024;

  const int nk = K >> 6;
  for (int kt = 0; kt < nk; ++kt) {
    const u16* a0 = Asrc + kt * 64;
    const u16* b0 = Bsrc + kt * 64;
#pragma unroll
    for (int is = 0; is < 4; ++is) {
      gl_lds16(a0 + (size_t)is * 32 * K, AsB + is * 4096);
      gl_lds16(b0 + (size_t)is * 32 * K, BsB + is * 4096);
    }
    __syncthreads();
#pragma unroll
    for (int kk = 0; kk < 2; ++kk) {
      bf16x8 af[4], bfr[4];
#pragma unroll
      for (int i = 0; i < 4; ++i) {
        af[i]  = *(const bf16x8*)(As + (wr * 64 + i * 16 + ln) * 64 + kk * 32 + g * 8);
        bfr[i] = *(const bf16x8*)(Bs + (wc * 64 + i * 16 + ln) * 64 + kk * 32 + g * 8);
      }
#pragma unroll
      for (int mi = 0; mi < 4; ++mi)
#pragma unroll
        for (int ni = 0; ni < 4; ++ni)
          acc[mi][ni] = mfma16(af[mi], bfr[ni], acc[mi][ni]);
    }
    __syncthreads();
  }
#pragma unroll
  for (int mi = 0; mi < 4; ++mi) {
#pragma unroll
    for (int ni = 0; ni < 4; ++ni) {
      int col = n0 + wc * 64 + ni * 16 + ln;
#pragma unroll
      for (int j = 0; j < 4; ++j) {
        int row = m0 + wr * 64 + mi * 16 + g * 4 + j;
        float v = acc[mi][ni][j];
        if (OUT_F32) {
          ((float*)Cout)[(size_t)row * N + col] = v + bias[col];
        } else {
          ((u16*)Cout)[(size_t)row * N + col] = f2bf(v);
        }
      }
    }
  }
}

// ---------------- flash attention ----------------
// 1D grid 2048, XCD-chunked swizzle; 256 threads = 4 waves; wave owns 16 q-rows.
// Swapped QK^T (S^T = mfma(K,Q)); P in registers (pi-permutation on both PV operands).
// Softmax: raw-logit units, p = exp2(fma(s, C2, -m*C2)); defer-max (THR=30 raw);
// P packed via v_cvt_pk_bf16_f32.
__global__ __launch_bounds__(256) void attn_kernel(const u16* __restrict__ qkv,
                                                   const u16* __restrict__ vT,
                                                   u16* __restrict__ obuf) {
  __shared__ __align__(16) u16 k_lds[64 * 64];
  __shared__ __align__(16) u16 v_lds[64 * 64];
  // XCD-chunked swizzle: 2048 wgs, 8 XCDs -> 256 consecutive work-items per XCD
  const int wg = blockIdx.x;
  const int j = (wg & 7) * 256 + (wg >> 3);
  const int qt = j & 31, h = (j >> 5) & 15, b = j >> 9;
  const int tid = threadIdx.x;
  const int w = tid >> 6, l = tid & 63, g = l >> 4, ln = l & 15;
  const int qrow = qt * 64 + w * 16 + ln;
  const size_t rs = 3 * DIM;
  const u16* qb = qkv + (size_t)(b * SEQ + qrow) * rs + h * HD;
  bf16x8 qf0 = *(const bf16x8*)(qb + g * 8);
  bf16x8 qf1 = *(const bf16x8*)(qb + 32 + g * 8);

  const int krow = tid >> 3;
  const int ksrccol = ((((tid & 7) << 4) ^ ((krow & 7) << 4))) >> 1;  // elements
  const u16* kbase = qkv + (size_t)b * SEQ * rs + DIM + h * HD;
  const u16* vtb = vT + (size_t)(b * HEADS + h) * 64 * 2048;
  char* kdst = (char*)k_lds + (size_t)w * 1024;
  char* vdst = (char*)v_lds + (size_t)w * 1024;

  const int swz = (ln & 7) << 4;

  float m = -1e30f, lsum = 0.f;
  f32x4 of[4];
#pragma unroll
  for (int i = 0; i < 4; ++i) of[i] = (f32x4){0.f, 0.f, 0.f, 0.f};

  for (int kv0 = 0; kv0 < SEQ; kv0 += 64) {
    const u16* ks0 = kbase + (size_t)(kv0 + krow) * rs + ksrccol;
    const u16* vs0 = vtb + (size_t)krow * 2048 + kv0 + ksrccol;
    gl_lds16(ks0, kdst);
    gl_lds16(ks0 + (size_t)32 * rs, kdst + 4096);
    gl_lds16(vs0, vdst);
    gl_lds16(vs0 + (size_t)32 * 2048, vdst + 4096);
    __syncthreads();

    // ---- S^T = K @ Q^T (raw logits) ----
    f32x4 sacc[4];
#pragma unroll
    for (int f = 0; f < 4; ++f) sacc[f] = (f32x4){0.f, 0.f, 0.f, 0.f};
#pragma unroll
    for (int f = 0; f < 4; ++f) {
      const char* kr = (const char*)k_lds + (f * 16 + ln) * 128;
      bf16x8 a0 = *(const bf16x8*)(kr + ((g * 16) ^ swz));
      bf16x8 a1 = *(const bf16x8*)(kr + ((64 | (g * 16)) ^ swz));
      sacc[f] = mfma16(a0, qf0, sacc[f]);
      sacc[f] = mfma16(a1, qf1, sacc[f]);
    }

    // ---- online softmax, raw units, defer-max ----
    float tm = -3e38f;
#pragma unroll
    for (int f = 0; f < 4; ++f)
#pragma unroll
      for (int jj = 0; jj < 4; ++jj) tm = fmaxf(tm, sacc[f][jj]);
    tm = fmaxf(tm, __shfl_xor(tm, 16));
    tm = fmaxf(tm, __shfl_xor(tm, 32));
    if (__any(tm > m + DEFER_THR)) {
      float mn = fmaxf(m, tm);
      float rs2 = __builtin_amdgcn_exp2f((m - mn) * C2);
      lsum *= rs2;
#pragma unroll
      for (int fd = 0; fd < 4; ++fd) of[fd] *= rs2;
      m = mn;
    }
    const float mc = m * C2;
    float ps = 0.f;
    union pu { unsigned wd[4]; bf16x8 b; } pf[2];
#pragma unroll
    for (int f = 0; f < 4; ++f) {
#pragma unroll
      for (int j2 = 0; j2 < 2; ++j2) {
        float p0 = __builtin_amdgcn_exp2f(fmaf(sacc[f][2 * j2], C2, -mc));
        float p1 = __builtin_amdgcn_exp2f(fmaf(sacc[f][2 * j2 + 1], C2, -mc));
        ps += p0 + p1;
        pf[f >> 1].wd[(f & 1) * 2 + j2] = cvt_pk_bf16(p0, p1);
      }
    }
    ps += __shfl_xor(ps, 16);
    ps += __shfl_xor(ps, 32);
    lsum += ps;

    // ---- PV: O^T += V^T @ P^T (pi(g,s) = 16*(s>>2) + 4g + (s&3) on both operands) ----
#pragma unroll
    for (int kk = 0; kk < 2; ++kk) {
#pragma unroll
      for (int fd = 0; fd < 4; ++fd) {
        const char* vr = (const char*)v_lds + (fd * 16 + ln) * 128;
        union { bf16x8 b; struct { u16x4 lo, hi; } hv; } fa;
        fa.hv.lo = *(const u16x4*)(vr + ((64 * kk + 8 * g) ^ swz));
        fa.hv.hi = *(const u16x4*)(vr + ((64 * kk + 32 + 8 * g) ^ swz));
        of[fd] = mfma16(fa.b, pf[kk].b, of[fd]);
      }
    }
    __syncthreads();
  }

  // epilogue: o[q][d] = O^T[d][q] / l ; d = fd*16 + 4g + j
  float linv = 1.f / lsum;
  u16* orow = obuf + (size_t)(b * SEQ + qrow) * DIM + h * HD;
#pragma unroll
  for (int fd = 0; fd < 4; ++fd) {
    unsigned w0 = cvt_pk_bf16(of[fd][0] * linv, of[fd][1] * linv);
    unsigned w1 = cvt_pk_bf16(of[fd][2] * linv, of[fd][3] * linv);
    unsigned* dst = (unsigned*)(orow + fd * 16 + g * 4);
    dst[0] = w0;
    dst[1] = w1;
  }
}

extern "C" void kernel_launch(void* const* d_in, const int* in_sizes, int n_in,
                              void* d_out, int out_size, void* d_ws, size_t ws_size,
                              hipStream_t stream) {
  const float* x     = (const float*)d_in[0];
  const float* w_in  = (const float*)d_in[1];
  const float* w_out = (const float*)d_in[2];
  const float* b_out = (const float*)d_in[3];
  float* out = (float*)d_out;

  char* ws = (char*)d_ws;
  u16* xb     = (u16*)(ws);                               // 16 MiB: x bf16 (dead after gemm1)
  u16* vT     = (u16*)(ws);                               // 16 MiB: aliases xb
  u16* w_inT  = (u16*)(ws + (size_t)16 * 1024 * 1024);    //  6 MiB
  u16* w_outT = (u16*)(ws + (size_t)22 * 1024 * 1024);    //  2 MiB
  u16* qkv    = (u16*)(ws + (size_t)24 * 1024 * 1024);    // 48 MiB
  u16* obuf   = (u16*)(ws + (size_t)72 * 1024 * 1024);    // 16 MiB

  cast_f32_bf16<<<8192, 256, 0, stream>>>(x, xb);
  transpose_cast<<<dim3(48, 16), 256, 0, stream>>>(w_in, w_inT, 1024, 3072);
  transpose_cast<<<dim3(16, 16), 256, 0, stream>>>(w_out, w_outT, 1024, 1024);
  gemm_bt<0><<<dim3(24, 64), 256, 0, stream>>>(xb, w_inT, qkv, nullptr, NROWS, 3 * DIM, DIM);
  transpose_v<<<dim3(32, 64), 256, 0, stream>>>(qkv, vT);
  attn_kernel<<<2048, 256, 0, stream>>>(qkv, vT, obuf);
  gemm_bt<1><<<dim3(8, 64), 256, 0, stream>>>(obuf, w_outT, out, b_out, NROWS, DIM, DIM);
}

// Round 5
// 230.842 us; speedup vs baseline: 1.5673x; 1.1059x over previous
//
#include <hip/hip_runtime.h>

typedef unsigned short u16;
typedef __bf16 bf16x8 __attribute__((ext_vector_type(8)));
typedef float f32x4 __attribute__((ext_vector_type(4)));
typedef unsigned short u16x4 __attribute__((ext_vector_type(4)));
typedef unsigned short u16x8 __attribute__((ext_vector_type(8)));

#define DIM 1024
#define HEADS 16
#define HD 64
#define SEQ 2048
#define BATCH 4
#define NROWS (BATCH*SEQ)
// raw-logit exp2 constant: 0.125 * log2(e)
#define C2 0.18033688f
// optimistic-softmax overflow trigger (~2^50)
#define THR_PS 1.125899907e15f

__device__ __forceinline__ u16 f2bf(float f) {
  union { float f; unsigned u; } v; v.f = f;
  unsigned r = v.u + 0x7FFFu + ((v.u >> 16) & 1u);   // RNE
  return (u16)(r >> 16);
}

__device__ __forceinline__ unsigned cvt_pk_bf16(float lo, float hi) {
  unsigned r;
  asm("v_cvt_pk_bf16_f32 %0, %1, %2" : "=v"(r) : "v"(lo), "v"(hi));
  return r;
}

__device__ __forceinline__ f32x4 mfma16(bf16x8 a, bf16x8 b, f32x4 c) {
  return __builtin_amdgcn_mfma_f32_16x16x32_bf16(a, b, c, 0, 0, 0);
}

// async global->LDS, 16B per lane; dst must be wave-uniform (HW adds lane*16)
__device__ __forceinline__ void gl_lds16(const void* g, void* l) {
  __builtin_amdgcn_global_load_lds(
      (const __attribute__((address_space(1))) void*)g,
      (__attribute__((address_space(3))) void*)l, 16, 0, 0);
}

// ---------------- cast x (f32 -> bf16), 4 elems/thread ----------------
__global__ __launch_bounds__(256) void cast_f32_bf16(const float* __restrict__ in,
                                                     u16* __restrict__ out) {
  int i = blockIdx.x * 256 + threadIdx.x;
  float4 v = ((const float4*)in)[i];
  u16x4 o = { f2bf(v.x), f2bf(v.y), f2bf(v.z), f2bf(v.w) };
  *(u16x4*)(out + (size_t)i * 4) = o;
}

// ------------- transpose+cast: in[R][C] f32 -> out[C][R] bf16 -------------
__global__ __launch_bounds__(256) void transpose_cast(const float* __restrict__ in,
                                                      u16* __restrict__ out,
                                                      int R, int C) {
  __shared__ u16 tile[64][65];
  int c0 = blockIdx.x * 64, r0 = blockIdx.y * 64;
  int tid = threadIdx.x;
#pragma unroll
  for (int i = 0; i < 16; ++i) {
    int idx = tid + i * 256;
    int r = idx >> 6, c = idx & 63;
    tile[c][r] = f2bf(in[(size_t)(r0 + r) * C + c0 + c]);
  }
  __syncthreads();
#pragma unroll
  for (int i = 0; i < 16; ++i) {
    int idx = tid + i * 256;
    int r = idx >> 6, c = idx & 63;
    out[(size_t)(c0 + r) * R + r0 + c] = tile[r][c];
  }
}

// ------------- V pre-transpose (kv sigma-permuted within 32-blocks) -------------
// vT[bh][d][pos]: for kv_local = 16a + 4g + j (within 32-block), pos = 8g + 4a + j.
// u32 (kv-pair) level: x = kv2 in 0..15 -> ((x&6)<<1) | ((x&8)>>2) | (x&1).
__global__ __launch_bounds__(256) void transpose_v(const u16* __restrict__ qkv,
                                                   u16* __restrict__ vT) {
  __shared__ unsigned t32[64][37];
  const int t = blockIdx.x, bh = blockIdx.y;
  const int b = bh >> 4, h = bh & 15;
  const u16* src = qkv + ((size_t)(b * SEQ + t * 64)) * 3072 + 2048 + h * 64;
  const int tid = threadIdx.x;
#pragma unroll
  for (int i = 0; i < 8; ++i) {
    int lin = tid + i * 256;
    int r2 = lin >> 6, c = lin & 63;
    unsigned lo = src[(size_t)(2 * r2) * 3072 + c];
    unsigned hi = src[(size_t)(2 * r2 + 1) * 3072 + c];
    t32[c][r2] = lo | (hi << 16);
  }
  __syncthreads();
  unsigned* dst = (unsigned*)(vT + (size_t)bh * 64 * 2048);
#pragma unroll
  for (int i = 0; i < 8; ++i) {
    int lin = tid + i * 256;
    int d = lin >> 5, r2 = lin & 31;
    int rp = (r2 & 16) | ((r2 & 6) << 1) | ((r2 & 8) >> 2) | (r2 & 1);
    dst[(size_t)d * 1024 + t * 32 + rp] = t32[d][r2];
  }
}

// ---------------- GEMM: C[M,N] = A[M,K] (bf16) @ BT[N,K]^T (bf16) ----------------
template<int OUT_F32>
__global__ __launch_bounds__(256) void gemm_bt(const u16* __restrict__ A,
                                               const u16* __restrict__ BT,
                                               void* __restrict__ Cout,
                                               const float* __restrict__ bias,
                                               int M, int N, int K) {
  __shared__ __align__(16) u16 As[128 * 64];
  __shared__ __align__(16) u16 Bs[128 * 64];
  const int tid = threadIdx.x;
  const int l = tid & 63, w = tid >> 6, g = l >> 4, ln = l & 15;
  const int m0 = blockIdx.y * 128, n0 = blockIdx.x * 128;
  const int wr = w >> 1, wc = w & 1;
  f32x4 acc[4][4];
#pragma unroll
  for (int i = 0; i < 4; ++i)
#pragma unroll
    for (int j = 0; j < 4; ++j) acc[i][j] = (f32x4){0.f, 0.f, 0.f, 0.f};

  const int srow = tid >> 3;
  const int scol = (tid & 7) * 8;
  const u16* Asrc = A  + (size_t)(m0 + srow) * K + scol;
  const u16* Bsrc = BT + (size_t)(n0 + srow) * K + scol;
  char* AsB = (char*)As + (size_t)w * 1024;
  char* BsB = (char*)Bs + (size_t)w * 1024;

  const int nk = K >> 6;
  for (int kt = 0; kt < nk; ++kt) {
    const u16* a0 = Asrc + kt * 64;
    const u16* b0 = Bsrc + kt * 64;
#pragma unroll
    for (int is = 0; is < 4; ++is) {
      gl_lds16(a0 + (size_t)is * 32 * K, AsB + is * 4096);
      gl_lds16(b0 + (size_t)is * 32 * K, BsB + is * 4096);
    }
    __syncthreads();
#pragma unroll
    for (int kk = 0; kk < 2; ++kk) {
      bf16x8 af[4], bfr[4];
#pragma unroll
      for (int i = 0; i < 4; ++i) {
        af[i]  = *(const bf16x8*)(As + (wr * 64 + i * 16 + ln) * 64 + kk * 32 + g * 8);
        bfr[i] = *(const bf16x8*)(Bs + (wc * 64 + i * 16 + ln) * 64 + kk * 32 + g * 8);
      }
#pragma unroll
      for (int mi = 0; mi < 4; ++mi)
#pragma unroll
        for (int ni = 0; ni < 4; ++ni)
          acc[mi][ni] = mfma16(af[mi], bfr[ni], acc[mi][ni]);
    }
    __syncthreads();
  }
#pragma unroll
  for (int mi = 0; mi < 4; ++mi) {
#pragma unroll
    for (int ni = 0; ni < 4; ++ni) {
      int col = n0 + wc * 64 + ni * 16 + ln;
#pragma unroll
      for (int j = 0; j < 4; ++j) {
        int row = m0 + wr * 64 + mi * 16 + g * 4 + j;
        float v = acc[mi][ni][j];
        if (OUT_F32) {
          ((float*)Cout)[(size_t)row * N + col] = v + bias[col];
        } else {
          ((u16*)Cout)[(size_t)row * N + col] = f2bf(v);
        }
      }
    }
  }
}

// ---------------- flash attention ----------------
// grid 1024 (XCD-chunked); 256 threads = 4 waves; 128 q-rows/block, 32 q-rows/wave
// (2 Q-fragments reuse each K/V LDS read -> LDS traffic halved vs 16-row waves).
// Swapped QK^T (S^T = mfma(K,Q)); P in registers; V sigma-permuted so PV A-frags are
// single b128 reads in the conflict-free 4*(g^t) dword pattern.
// Optimistic softmax: no per-tile max; overflow trigger via ps > 2^50 (tile 0 triggers
// via ps = inf and initializes m).
__global__ __launch_bounds__(256) void attn_kernel(const u16* __restrict__ qkv,
                                                   const u16* __restrict__ vT,
                                                   u16* __restrict__ obuf) {
  __shared__ __align__(16) u16 k_lds[64 * 64];
  __shared__ __align__(16) u16 v_lds[64 * 64];
  const int wg = blockIdx.x;
  const int j = (wg & 7) * 128 + (wg >> 3);     // 1024 = 8 XCD x 128
  const int qt = j & 15, h = (j >> 4) & 15, b = j >> 8;
  const int tid = threadIdx.x;
  const int w = tid >> 6, l = tid & 63, g = l >> 4, ln = l & 15;
  const int qbase = qt * 128 + w * 32;
  const size_t rs = 3 * DIM;

  bf16x8 qf[2][2];
#pragma unroll
  for (int e = 0; e < 2; ++e) {
    const u16* qb = qkv + (size_t)(b * SEQ + qbase + e * 16 + ln) * rs + h * HD;
    qf[e][0] = *(const bf16x8*)(qb + g * 8);
    qf[e][1] = *(const bf16x8*)(qb + 32 + g * 8);
  }

  const int krow = tid >> 3;
  const int ksrccol = ((((tid & 7) << 4) ^ ((krow & 7) << 4))) >> 1;  // elements
  const u16* kbase = qkv + (size_t)b * SEQ * rs + DIM + h * HD;
  const u16* vtb = vT + (size_t)(b * HEADS + h) * 64 * 2048;
  char* kdst = (char*)k_lds + (size_t)w * 1024;
  char* vdst = (char*)v_lds + (size_t)w * 1024;
  const int swz = (ln & 7) << 4;

  float m[2] = { -1e30f, -1e30f }, lsum[2] = { 0.f, 0.f };
  f32x4 of[2][4];
#pragma unroll
  for (int e = 0; e < 2; ++e)
#pragma unroll
    for (int i = 0; i < 4; ++i) of[e][i] = (f32x4){0.f, 0.f, 0.f, 0.f};

  for (int kv0 = 0; kv0 < SEQ; kv0 += 64) {
    const u16* ks0 = kbase + (size_t)(kv0 + krow) * rs + ksrccol;
    const u16* vs0 = vtb + (size_t)krow * 2048 + kv0 + ksrccol;
    gl_lds16(ks0, kdst);
    gl_lds16(ks0 + (size_t)32 * rs, kdst + 4096);
    gl_lds16(vs0, vdst);
    gl_lds16(vs0 + (size_t)32 * 2048, vdst + 4096);
    __syncthreads();

    // ---- S^T = K @ Q^T (raw logits), K frags reused across both Q frags ----
    f32x4 sacc[2][4];
#pragma unroll
    for (int e = 0; e < 2; ++e)
#pragma unroll
      for (int f = 0; f < 4; ++f) sacc[e][f] = (f32x4){0.f, 0.f, 0.f, 0.f};
#pragma unroll
    for (int f = 0; f < 4; ++f) {
      const char* kr = (const char*)k_lds + (f * 16 + ln) * 128;
      bf16x8 a0 = *(const bf16x8*)(kr + ((g * 16) ^ swz));
      bf16x8 a1 = *(const bf16x8*)(kr + ((64 | (g * 16)) ^ swz));
#pragma unroll
      for (int e = 0; e < 2; ++e) {
        sacc[e][f] = mfma16(a0, qf[e][0], sacc[e][f]);
        sacc[e][f] = mfma16(a1, qf[e][1], sacc[e][f]);
      }
    }

    // ---- optimistic softmax: p = exp2(fma(s, C2, -m*C2)), no per-tile max ----
    union pu { unsigned wd[4]; bf16x8 bv; } pf[2][2];
    float ps[2];
#pragma unroll
    for (int e = 0; e < 2; ++e) {
      const float mc = m[e] * C2;
      float s2 = 0.f;
#pragma unroll
      for (int f = 0; f < 4; ++f)
#pragma unroll
        for (int j2 = 0; j2 < 2; ++j2) {
          float p0 = __builtin_amdgcn_exp2f(fmaf(sacc[e][f][2 * j2], C2, -mc));
          float p1 = __builtin_amdgcn_exp2f(fmaf(sacc[e][f][2 * j2 + 1], C2, -mc));
          s2 += p0 + p1;
          pf[e][f >> 1].wd[(f & 1) * 2 + j2] = cvt_pk_bf16(p0, p1);
        }
      s2 += __shfl_xor(s2, 16);
      s2 += __shfl_xor(s2, 32);
      ps[e] = s2;
    }
    if (__any(fmaxf(ps[0], ps[1]) > THR_PS)) {   // rare: tile 0 + pathological growth
#pragma unroll
      for (int e = 0; e < 2; ++e) {
        float tm = -3e38f;
#pragma unroll
        for (int f = 0; f < 4; ++f)
#pragma unroll
          for (int jj = 0; jj < 4; ++jj) tm = fmaxf(tm, sacc[e][f][jj]);
        tm = fmaxf(tm, __shfl_xor(tm, 16));
        tm = fmaxf(tm, __shfl_xor(tm, 32));
        float mn = fmaxf(m[e], tm);
        float rc = __builtin_amdgcn_exp2f((m[e] - mn) * C2);
        lsum[e] *= rc;
#pragma unroll
        for (int fd = 0; fd < 4; ++fd) of[e][fd] *= rc;
        m[e] = mn;
        const float mc = mn * C2;
        float s2 = 0.f;
#pragma unroll
        for (int f = 0; f < 4; ++f)
#pragma unroll
          for (int j2 = 0; j2 < 2; ++j2) {
            float p0 = __builtin_amdgcn_exp2f(fmaf(sacc[e][f][2 * j2], C2, -mc));
            float p1 = __builtin_amdgcn_exp2f(fmaf(sacc[e][f][2 * j2 + 1], C2, -mc));
            s2 += p0 + p1;
            pf[e][f >> 1].wd[(f & 1) * 2 + j2] = cvt_pk_bf16(p0, p1);
          }
        s2 += __shfl_xor(s2, 16);
        s2 += __shfl_xor(s2, 32);
        ps[e] = s2;
      }
    }
    lsum[0] += ps[0];
    lsum[1] += ps[1];

    // ---- PV: O^T += V^T @ P^T; single b128 A-frag per (kk,fd), reused over e ----
#pragma unroll
    for (int kk = 0; kk < 2; ++kk)
#pragma unroll
      for (int fd = 0; fd < 4; ++fd) {
        const char* vr = (const char*)v_lds + (fd * 16 + ln) * 128;
        bf16x8 fa = *(const bf16x8*)(vr + ((kk * 64 + g * 16) ^ swz));
#pragma unroll
        for (int e = 0; e < 2; ++e)
          of[e][fd] = mfma16(fa, pf[e][kk].bv, of[e][fd]);
      }
    __syncthreads();
  }

  // epilogue: o[q][d] = O^T[d][q] / l ; d = fd*16 + 4g + j
#pragma unroll
  for (int e = 0; e < 2; ++e) {
    float linv = 1.f / lsum[e];
    u16* orow = obuf + (size_t)(b * SEQ + qbase + e * 16 + ln) * DIM + h * HD;
#pragma unroll
    for (int fd = 0; fd < 4; ++fd) {
      unsigned w0 = cvt_pk_bf16(of[e][fd][0] * linv, of[e][fd][1] * linv);
      unsigned w1 = cvt_pk_bf16(of[e][fd][2] * linv, of[e][fd][3] * linv);
      unsigned* dst = (unsigned*)(orow + fd * 16 + g * 4);
      dst[0] = w0;
      dst[1] = w1;
    }
  }
}

extern "C" void kernel_launch(void* const* d_in, const int* in_sizes, int n_in,
                              void* d_out, int out_size, void* d_ws, size_t ws_size,
                              hipStream_t stream) {
  const float* x     = (const float*)d_in[0];
  const float* w_in  = (const float*)d_in[1];
  const float* w_out = (const float*)d_in[2];
  const float* b_out = (const float*)d_in[3];
  float* out = (float*)d_out;

  char* ws = (char*)d_ws;
  u16* xb     = (u16*)(ws);                               // 16 MiB: x bf16 (dead after gemm1)
  u16* vT     = (u16*)(ws);                               // 16 MiB: aliases xb
  u16* w_inT  = (u16*)(ws + (size_t)16 * 1024 * 1024);    //  6 MiB
  u16* w_outT = (u16*)(ws + (size_t)22 * 1024 * 1024);    //  2 MiB
  u16* qkv    = (u16*)(ws + (size_t)24 * 1024 * 1024);    // 48 MiB
  u16* obuf   = (u16*)(ws + (size_t)72 * 1024 * 1024);    // 16 MiB

  cast_f32_bf16<<<8192, 256, 0, stream>>>(x, xb);
  transpose_cast<<<dim3(48, 16), 256, 0, stream>>>(w_in, w_inT, 1024, 3072);
  transpose_cast<<<dim3(16, 16), 256, 0, stream>>>(w_out, w_outT, 1024, 1024);
  gemm_bt<0><<<dim3(24, 64), 256, 0, stream>>>(xb, w_inT, qkv, nullptr, NROWS, 3 * DIM, DIM);
  transpose_v<<<dim3(32, 64), 256, 0, stream>>>(qkv, vT);
  attn_kernel<<<1024, 256, 0, stream>>>(qkv, vT, obuf);
  gemm_bt<1><<<dim3(8, 64), 256, 0, stream>>>(obuf, w_outT, out, b_out, NROWS, DIM, DIM);
}